// Round 3
// baseline (285.162 us; speedup 1.0000x reference)
//
#include <hip/hip_runtime.h>

#define HALF 128
#define NMAT 16384   // 128*128
#define NTOK 131072  // 32*4096

typedef float f4 __attribute__((ext_vector_type(4)));

// ---------------------------------------------------------------------------
// K1: fused Cayley -> QT.  Q^T = N^{-1}(2I - N) = 2 N^{-1} - I,  N = I + A/2.
// BLOCKED Gauss-Jordan (panel b=16): 8 block-steps x 2 barriers.
// NOW 1024 THREADS (was 512): thread owns 16 rows of one column (was 32) ->
// per-step update work halves (256 fma, 64 b128 broadcasts) and 16 waves hide
// the LDS issue latency.  Same elimination order, same per-element fma
// association as the verified kernel -> bit-identical output.
// ---------------------------------------------------------------------------
__global__ __launch_bounds__(1024) void cayley_qt(const float* __restrict__ prim,
                                                  float* __restrict__ QT) {
    __shared__ __align__(16) float Xs[128 * 129];     // padded input stage
    __shared__ __align__(16) float CpT[2][16][132];   // panel cols, [m][r]
    __shared__ __align__(16) float Rp [2][16][128];   // panel rows, [j][c]
    __shared__ __align__(16) float Dcol[2][16][20];   // Dcol[j][m] = Dinv[m][j]

    const int b = blockIdx.x;
    const float* __restrict__ X = prim + b * NMAT;
    const int t  = threadIdx.x;
    const int c  = t & 127;          // owned column
    const int q  = t >> 7;           // row group (0..7), wave-uniform
    const int r0 = q << 4;           // owns rows r0..r0+15

    for (int idx4 = t; idx4 < 4096; idx4 += 1024) {
        int gi = idx4 << 2;
        float4 v = *(const float4*)(X + gi);
        int r = gi >> 7, cc = gi & 127;
        float* p = &Xs[r * 129 + cc];
        p[0] = v.x; p[1] = v.y; p[2] = v.z; p[3] = v.w;
    }
    __syncthreads();

    // reg[i] = N[r0+i][c];  A = tril(X) - tril(X)^T
    float reg[16];
    #pragma unroll
    for (int i = 0; i < 16; ++i) {
        int r  = r0 + i;
        int mx = r > c ? r : c;
        int mn = r ^ c ^ mx;
        float x = Xs[mx * 129 + mn];
        reg[i] = (r == c) ? 1.0f : (r > c ? 0.5f * x : -0.5f * x);
    }

    #pragma unroll
    for (int s = 0; s < 8; ++s) {
        const int  p     = s & 1;
        const int  k0    = s << 4;
        const bool panel = (c >= k0) && (c < k0 + 16);
        // rows K = [16s, 16s+16) live entirely in row-group q == s

        if (panel) {
            const int m = c - k0;
            #pragma unroll
            for (int i = 0; i < 16; i += 4)
                *(float4*)&CpT[p][m][r0 + i] =
                    make_float4(reg[i], reg[i+1], reg[i+2], reg[i+3]);
        }
        if (q == s) {
            #pragma unroll
            for (int j = 0; j < 16; ++j) Rp[p][j][c] = reg[j];
        }
        __syncthreads();

        if (t < 64) {
            const int cp = t & 15, q4 = t >> 4;
            float dd[4];
            #pragma unroll
            for (int i = 0; i < 4; ++i) dd[i] = Rp[p][q4 * 4 + i][k0 + cp];
            #pragma unroll
            for (int k = 0; k < 16; ++k) {
                float cv[4];
                #pragma unroll
                for (int i = 0; i < 4; ++i) cv[i] = __shfl(dd[i], (q4 << 4) | k);
                float rv   = __shfl(dd[k & 3], ((k >> 2) << 4) | cp);
                float dkk  = __shfl(rv, k);
                float dinv = 1.0f / dkk;
                float sv   = rv * dinv;
                bool  own  = (cp == k);
                float rf   = own ? dinv : sv;
                #pragma unroll
                for (int i = 0; i < 4; ++i)
                    dd[i] = own ? (-dd[i] * dinv) : fmaf(-cv[i], sv, dd[i]);
                dd[k & 3] = (q4 == (k >> 2)) ? rf : dd[k & 3];
            }
            #pragma unroll
            for (int i = 0; i < 4; ++i) Dcol[p][cp][q4 * 4 + i] = dd[i];
        }
        __syncthreads();

        float coeff[16];
        if (!panel) {
            #pragma unroll
            for (int j = 0; j < 16; ++j) coeff[j] = 0.0f;
            #pragma unroll
            for (int j = 0; j < 16; ++j) {
                float rpj = Rp[p][j][c];
                #pragma unroll
                for (int mq = 0; mq < 16; mq += 4) {
                    float4 dv = *(const float4*)&Dcol[p][j][mq];
                    coeff[mq+0] = fmaf(dv.x, rpj, coeff[mq+0]);
                    coeff[mq+1] = fmaf(dv.y, rpj, coeff[mq+1]);
                    coeff[mq+2] = fmaf(dv.z, rpj, coeff[mq+2]);
                    coeff[mq+3] = fmaf(dv.w, rpj, coeff[mq+3]);
                }
            }
        } else {
            const int mp = c - k0;
            #pragma unroll
            for (int j = 0; j < 16; ++j) coeff[j] = Dcol[p][mp][j];
            #pragma unroll
            for (int i = 0; i < 16; ++i) reg[i] = 0.0f;
        }

        #pragma unroll
        for (int m = 0; m < 16; ++m) {
            float cm = coeff[m];
            #pragma unroll
            for (int i = 0; i < 16; i += 4) {
                float4 c4 = *(const float4*)&CpT[p][m][r0 + i];
                reg[i+0] = fmaf(-c4.x, cm, reg[i+0]);
                reg[i+1] = fmaf(-c4.y, cm, reg[i+1]);
                reg[i+2] = fmaf(-c4.z, cm, reg[i+2]);
                reg[i+3] = fmaf(-c4.w, cm, reg[i+3]);
            }
        }
        if (q == s) {
            #pragma unroll
            for (int j = 0; j < 16; ++j) reg[j] = coeff[j];
        }
    }

    float* __restrict__ out = QT + b * NMAT;
    #pragma unroll
    for (int i = 0; i < 16; ++i) {
        int r = r0 + i;
        out[r * HALF + c] = 2.0f * reg[i] - (r == c ? 1.0f : 0.0f);
    }
}

// ---------------------------------------------------------------------------
// K2a: rows [0,256) from identity, steps d=0..6.  BARRIER-FREE: vs[*][rg] is
// written and read only by wave rg (rg = t>>6 = wave id), so __syncthreads
// was pure overhead AND blocked cross-step pipelining of the (data-
// independent) global Q loads.  Within-wave LDS RAW ordered by lgkmcnt.
// Same fma association -> bit-identical.
// ---------------------------------------------------------------------------
__global__ __launch_bounds__(256) void path_base(const float* __restrict__ QT,
                                                 const float* __restrict__ ident,
                                                 float* __restrict__ P) {
    __shared__ __align__(16) float vs[2][4][HALF];
    const int t    = threadIdx.x;
    const int rg   = t >> 6;                 // row in block (0..3), one wave each
    const int jj   = (t & 63) << 1;          // 2-col chunk
    const int v    = (blockIdx.x << 2) + rg;
    const int vmax = (blockIdx.x << 2) + 3;

    float2 cv = *(const float2*)&ident[jj];
    *(float2*)&vs[0][rg][jj] = cv;

    int cur = 0;
    for (int d = 0; d < 8; ++d) {
        if ((vmax >> (d + 1)) == 0) break;           // block-uniform
        const bool valid = (v >> (d + 1)) > 0;
        const float* __restrict__ Qm = QT + (((v >> d) & 1) ? NMAT : 0);
        float2 acc = make_float2(0.f, 0.f);
        #pragma unroll 4
        for (int cc = 0; cc < 128; cc += 4) {
            float4 v4 = *(const float4*)&vs[cur][rg][cc];
            float2 q0 = *(const float2*)&Qm[(cc+0)*HALF + jj];
            float2 q1 = *(const float2*)&Qm[(cc+1)*HALF + jj];
            float2 q2 = *(const float2*)&Qm[(cc+2)*HALF + jj];
            float2 q3 = *(const float2*)&Qm[(cc+3)*HALF + jj];
            acc.x = fmaf(v4.x,q0.x, fmaf(v4.y,q1.x, fmaf(v4.z,q2.x, fmaf(v4.w,q3.x, acc.x))));
            acc.y = fmaf(v4.x,q0.y, fmaf(v4.y,q1.y, fmaf(v4.z,q2.y, fmaf(v4.w,q3.y, acc.y))));
        }
        if (valid) cv = acc;
        *(float2*)&vs[cur ^ 1][rg][jj] = cv;         // wave-private slot
        cur ^= 1;
    }
    *(float2*)&P[v * HALF + jj] = cv;
}

// ---------------------------------------------------------------------------
// K2b: rows [256,4096), k-grouped, column-parallel.  UNCHANGED (verified;
// cross-wave Q-read sharing needs the pair barrier, alternatives re-inflate
// L2 traffic 2-4x).
// ---------------------------------------------------------------------------
__global__ __launch_bounds__(256) void path_upper(const float* __restrict__ QT,
                                                  float* __restrict__ P) {
    __shared__ __align__(16) float vs[2][8][HALF];   // double-buffered row vals
    const int t  = threadIdx.x;
    const int j  = t & 127;                // owned output column
    const int h  = t >> 7;                 // row half: rows h*4 .. h*4+3
    const int k  = 2 + (blockIdx.x >> 4);  // 30 k-values x 16 blocks = 480
    const int r0 = (blockIdx.x & 15) << 3; // 8 residues per block

    float acc[4];
    #pragma unroll
    for (int rr = 0; rr < 4; ++rr)
        acc[rr] = P[(128 + r0 + h * 4 + rr) * HALF + j];

    int p = 0;
    for (int d = 7; d < 13; ++d) {
        if ((k >> (d - 6)) == 0) break;              // block-uniform
        const float* __restrict__ Qm = QT + (((k >> (d - 7)) & 1) ? NMAT : 0);
        #pragma unroll
        for (int rr = 0; rr < 4; ++rr) vs[p][h * 4 + rr][j] = acc[rr];
        __syncthreads();                             // other buffer still live

        float nacc[4] = {0.f, 0.f, 0.f, 0.f};
        #pragma unroll 4
        for (int cc = 0; cc < 128; cc += 4) {
            float q0 = Qm[(cc + 0) * HALF + j];      // coalesced global dword
            float q1 = Qm[(cc + 1) * HALF + j];
            float q2 = Qm[(cc + 2) * HALF + j];
            float q3 = Qm[(cc + 3) * HALF + j];
            #pragma unroll
            for (int rr = 0; rr < 4; ++rr) {
                float4 v4 = *(const float4*)&vs[p][h * 4 + rr][cc];  // broadcast
                nacc[rr] = fmaf(v4.x, q0,
                           fmaf(v4.y, q1,
                           fmaf(v4.z, q2,
                           fmaf(v4.w, q3, nacc[rr]))));
            }
        }
        #pragma unroll
        for (int rr = 0; rr < 4; ++rr) acc[rr] = nacc[rr];
        p ^= 1;                                      // next step: other buffer
    }

    #pragma unroll
    for (int rr = 0; rr < 4; ++rr)
        P[((k << 7) | (r0 + h * 4 + rr)) * HALF + j] = acc[rr];
}

// ---------------------------------------------------------------------------
// K3: emit [B,S,256] = content ++ pos.  UNCHANGED (at ~21 us write floor;
// nontemporal stores keep P hot in L2 for the gathers).
// ---------------------------------------------------------------------------
__global__ __launch_bounds__(256) void emit_out(const int* __restrict__ tt,
                                                const int* __restrict__ tv,
                                                const int* __restrict__ np,
                                                const float* __restrict__ P,
                                                const float* __restrict__ emb,
                                                float* __restrict__ out) {
    const int i  = (blockIdx.x << 2) + (threadIdx.x >> 6);
    const int jj = (threadIdx.x & 63) << 2;
    const int ty = tt[i];
    const int v  = tv[i];
    f4 val;
    if (jj < 128) {
        if (ty == 0)      val = *(const f4*)&emb[jj];
        else if (ty == 1) val = *(const f4*)&emb[(v + 1) * HALF + jj];
        else if (ty == 2) val = *(const f4*)&emb[(v + 5) * HALF + jj];
        else if (ty == 4) {
            int vc = v < 0 ? 0 : (v > 4095 ? 4095 : v);
            val = *(const f4*)&P[vc * HALF + jj];
        } else if (v == -1) val = *(const f4*)&emb[10 * HALF + jj];
        else { f4 z = {0.f, 0.f, 0.f, 0.f}; val = z; }
    } else {
        const int p = np[i];
        val = *(const f4*)&P[p * HALF + (jj - 128)];
    }
    __builtin_nontemporal_store(val, (f4*)&out[i * 256 + jj]);
}

extern "C" void kernel_launch(void* const* d_in, const int* in_sizes, int n_in,
                              void* d_out, int out_size, void* d_ws, size_t ws_size,
                              hipStream_t stream) {
    const int*   token_types = (const int*)  d_in[0];
    const int*   token_vals  = (const int*)  d_in[1];
    const int*   node_pos    = (const int*)  d_in[2];
    const float* prim        = (const float*)d_in[3];
    const float* ident       = (const float*)d_in[4];
    const float* emb         = (const float*)d_in[5];
    float* out = (float*)d_out;

    // workspace: QT[2][128][128] | (gap) | P[4096][128]
    float* QT = (float*)d_ws;
    float* P  = (float*)((char*)d_ws + 262144);

    cayley_qt  <<<2,   1024, 0, stream>>>(prim, QT);
    path_base  <<<64,  256,  0, stream>>>(QT, ident, P);    // rows [0,256)
    path_upper <<<480, 256,  0, stream>>>(QT, P);           // rows [256,4096)
    emit_out   <<<NTOK / 4, 256, 0, stream>>>(token_types, token_vals, node_pos,
                                              P, emb, out);
}

// Round 4
// 271.740 us; speedup vs baseline: 1.0494x; 1.0494x over previous
//
#include <hip/hip_runtime.h>

#define HALF 128
#define NMAT 16384   // 128*128
#define NTOK 131072  // 32*4096

typedef float f4 __attribute__((ext_vector_type(4)));

// ---------------------------------------------------------------------------
// K1: fused Cayley -> QT.  Q^T = N^{-1}(2I - N) = 2 N^{-1} - I,  N = I + A/2.
// BLOCKED Gauss-Jordan (panel b=16), 8 block-steps.  ROUND-4 RESTRUCTURE:
// thread owns a 4x8 TILE (was: 1 column x 32 rows), so coeff/update LDS reads
// are per-lane-distinct b128 (66 instr-equiv/wave/step) instead of wave
// broadcasts (192) -- K1 was LDS-instruction-throughput bound (round-3
// evidence: doubling threads was neutral; total LDS instr invariant).
// RB[m][c] = per-column coeff vector, built once cooperatively.
// Per-element fma order (m ascending, j ascending) identical to the verified
// kernel -> bit-identical output.
// ---------------------------------------------------------------------------
__global__ __launch_bounds__(512) void cayley_qt(const float* __restrict__ prim,
                                                 float* __restrict__ QT) {
    __shared__ __align__(16) float Xs[128 * 129];   // padded input stage
    __shared__ __align__(16) float Cp[2][128][20];  // C panel, [r][m] (dbuf)
    __shared__ __align__(16) float Rp[16][132];     // R panel, [j][c]
    __shared__ __align__(16) float Dcol[16][20];    // Dcol[j][m] = Dinv[m][j]
    __shared__ __align__(16) float RB[16][132];     // coeff: RB[m][c]

    const int b = blockIdx.x;
    const float* __restrict__ X = prim + b * NMAT;
    const int t  = threadIdx.x;
    const int rg = t >> 4;           // row group: rows 4rg..4rg+3
    const int cg = t & 15;           // col group: cols 8cg..8cg+7

    for (int idx4 = t; idx4 < 4096; idx4 += 512) {
        int gi = idx4 << 2;
        float4 v = *(const float4*)(X + gi);
        int r = gi >> 7, cc = gi & 127;
        float* xp = &Xs[r * 129 + cc];
        xp[0] = v.x; xp[1] = v.y; xp[2] = v.z; xp[3] = v.w;
    }
    __syncthreads();

    // reg[i][jj] = N[4rg+i][8cg+jj];  A = tril(X) - tril(X)^T
    float reg[4][8];
    #pragma unroll
    for (int i = 0; i < 4; ++i) {
        const int r = (rg << 2) + i;
        #pragma unroll
        for (int jj = 0; jj < 8; ++jj) {
            const int c = (cg << 3) + jj;
            int mx = r > c ? r : c;
            int mn = r ^ c ^ mx;
            float x = Xs[mx * 129 + mn];
            reg[i][jj] = (r == c) ? 1.0f : (r > c ? 0.5f * x : -0.5f * x);
        }
    }

    #pragma unroll
    for (int s = 0; s < 8; ++s) {
        const int  p    = s & 1;
        const int  k0   = s << 4;
        const bool pubC = (cg >> 1) == s;   // this tile's 8 cols inside K
        const bool pubR = (rg >> 2) == s;   // this tile's 4 rows inside K

        // ---- A. publish pre-step panels
        if (pubC) {
            const int mb = (cg & 1) << 3;   // m = (8cg+jj) - k0 = mb + jj
            #pragma unroll
            for (int i = 0; i < 4; ++i) {
                *(float4*)&Cp[p][(rg << 2) + i][mb] =
                    make_float4(reg[i][0], reg[i][1], reg[i][2], reg[i][3]);
                *(float4*)&Cp[p][(rg << 2) + i][mb + 4] =
                    make_float4(reg[i][4], reg[i][5], reg[i][6], reg[i][7]);
            }
        }
        if (pubR) {
            const int jb = (rg & 3) << 2;   // local row j = jb + i
            #pragma unroll
            for (int i = 0; i < 4; ++i) {
                *(float4*)&Rp[jb + i][cg << 3] =
                    make_float4(reg[i][0], reg[i][1], reg[i][2], reg[i][3]);
                *(float4*)&Rp[jb + i][(cg << 3) + 4] =
                    make_float4(reg[i][4], reg[i][5], reg[i][6], reg[i][7]);
            }
        }
        __syncthreads();

        // ---- C. wave 0: invert D (16x16) in registers, shuffle-based GJ
        if (t < 64) {
            const int cp = t & 15, q4 = t >> 4;
            float dd[4];
            #pragma unroll
            for (int i = 0; i < 4; ++i) dd[i] = Rp[q4 * 4 + i][k0 + cp];
            #pragma unroll
            for (int k = 0; k < 16; ++k) {
                float cv[4];
                #pragma unroll
                for (int i = 0; i < 4; ++i) cv[i] = __shfl(dd[i], (q4 << 4) | k);
                float rv   = __shfl(dd[k & 3], ((k >> 2) << 4) | cp);
                float dkk  = __shfl(rv, k);
                float dinv = 1.0f / dkk;
                float sv   = rv * dinv;
                bool  own  = (cp == k);
                float rf   = own ? dinv : sv;
                #pragma unroll
                for (int i = 0; i < 4; ++i)
                    dd[i] = own ? (-dd[i] * dinv) : fmaf(-cv[i], sv, dd[i]);
                dd[k & 3] = (q4 == (k >> 2)) ? rf : dd[k & 3];
            }
            #pragma unroll
            for (int i = 0; i < 4; ++i) Dcol[cp][q4 * 4 + i] = dd[i];
        }
        __syncthreads();

        // ---- E. build RB[m][c] cooperatively (512 thr x 4 entries)
        {
            const int m  = t >> 5;
            const int qd = t & 31;
            const int cb = qd << 2;          // cols cb..cb+3
            float4 acc;
            if ((qd >> 2) == s) {
                // panel cols: RB[m][k0+mp] = Dinv[m][mp] = Dcol[mp][m] (copy)
                acc.x = Dcol[cb + 0 - k0][m];
                acc.y = Dcol[cb + 1 - k0][m];
                acc.z = Dcol[cb + 2 - k0][m];
                acc.w = Dcol[cb + 3 - k0][m];
            } else {
                acc = make_float4(0.f, 0.f, 0.f, 0.f);
                #pragma unroll
                for (int j = 0; j < 16; ++j) {          // j ascending (as old)
                    float  dj = Dcol[j][m];
                    float4 r4 = *(const float4*)&Rp[j][cb];
                    acc.x = fmaf(dj, r4.x, acc.x);
                    acc.y = fmaf(dj, r4.y, acc.y);
                    acc.z = fmaf(dj, r4.z, acc.z);
                    acc.w = fmaf(dj, r4.w, acc.w);
                }
            }
            *(float4*)&RB[m][cb] = acc;
        }
        __syncthreads();

        // ---- G. rank-16 update on the 4x8 tile (C in regs, RB streamed)
        float crs[4][16];
        #pragma unroll
        for (int i = 0; i < 4; ++i)
            #pragma unroll
            for (int mq = 0; mq < 4; ++mq) {
                float4 v = *(const float4*)&Cp[p][(rg << 2) + i][mq << 2];
                crs[i][4 * mq + 0] = v.x; crs[i][4 * mq + 1] = v.y;
                crs[i][4 * mq + 2] = v.z; crs[i][4 * mq + 3] = v.w;
            }
        if (pubC) {
            #pragma unroll
            for (int i = 0; i < 4; ++i)
                #pragma unroll
                for (int jj = 0; jj < 8; ++jj) reg[i][jj] = 0.0f;
        }
        #pragma unroll
        for (int m = 0; m < 16; ++m) {       // m ascending (as old)
            float4 rb0 = *(const float4*)&RB[m][cg << 3];
            float4 rb1 = *(const float4*)&RB[m][(cg << 3) + 4];
            #pragma unroll
            for (int i = 0; i < 4; ++i) {
                float cm = crs[i][m];
                reg[i][0] = fmaf(-cm, rb0.x, reg[i][0]);
                reg[i][1] = fmaf(-cm, rb0.y, reg[i][1]);
                reg[i][2] = fmaf(-cm, rb0.z, reg[i][2]);
                reg[i][3] = fmaf(-cm, rb0.w, reg[i][3]);
                reg[i][4] = fmaf(-cm, rb1.x, reg[i][4]);
                reg[i][5] = fmaf(-cm, rb1.y, reg[i][5]);
                reg[i][6] = fmaf(-cm, rb1.z, reg[i][6]);
                reg[i][7] = fmaf(-cm, rb1.w, reg[i][7]);
            }
        }
        if (pubR) {                          // rows K: W[K,:] = RB
            const int jb = (rg & 3) << 2;
            #pragma unroll
            for (int i = 0; i < 4; ++i) {
                float4 a = *(const float4*)&RB[jb + i][cg << 3];
                float4 b2 = *(const float4*)&RB[jb + i][(cg << 3) + 4];
                reg[i][0] = a.x;  reg[i][1] = a.y;  reg[i][2] = a.z;  reg[i][3] = a.w;
                reg[i][4] = b2.x; reg[i][5] = b2.y; reg[i][6] = b2.z; reg[i][7] = b2.w;
            }
        }
        // next step's publish barrier guards Cp buffer swap; Rp/Dcol/RB
        // read-write pairs are each separated by >=1 barrier (single-buffered).
    }

    float* __restrict__ out = QT + b * NMAT;
    #pragma unroll
    for (int i = 0; i < 4; ++i) {
        const int r  = (rg << 2) + i;
        const int c0 = cg << 3;
        float4 o0, o1;
        o0.x = 2.0f * reg[i][0] - (r == c0 + 0 ? 1.0f : 0.0f);
        o0.y = 2.0f * reg[i][1] - (r == c0 + 1 ? 1.0f : 0.0f);
        o0.z = 2.0f * reg[i][2] - (r == c0 + 2 ? 1.0f : 0.0f);
        o0.w = 2.0f * reg[i][3] - (r == c0 + 3 ? 1.0f : 0.0f);
        o1.x = 2.0f * reg[i][4] - (r == c0 + 4 ? 1.0f : 0.0f);
        o1.y = 2.0f * reg[i][5] - (r == c0 + 5 ? 1.0f : 0.0f);
        o1.z = 2.0f * reg[i][6] - (r == c0 + 6 ? 1.0f : 0.0f);
        o1.w = 2.0f * reg[i][7] - (r == c0 + 7 ? 1.0f : 0.0f);
        *(float4*)&out[r * HALF + c0]     = o0;
        *(float4*)&out[r * HALF + c0 + 4] = o1;
    }
}

// ---------------------------------------------------------------------------
// K2a: rows [0,256) from identity, steps d=0..6.  ROUND-2 VERIFIED FORM
// (barriered; barrier-free variant regressed in round 3).
// ---------------------------------------------------------------------------
__global__ __launch_bounds__(256) void path_base(const float* __restrict__ QT,
                                                 const float* __restrict__ ident,
                                                 float* __restrict__ P) {
    __shared__ __align__(16) float vs[2][4][HALF];
    const int t    = threadIdx.x;
    const int rg   = t >> 6;                 // row in block (0..3), one wave each
    const int jj   = (t & 63) << 1;          // 2-col chunk
    const int v    = (blockIdx.x << 2) + rg;
    const int vmax = (blockIdx.x << 2) + 3;

    float2 cv = *(const float2*)&ident[jj];
    *(float2*)&vs[0][rg][jj] = cv;
    __syncthreads();

    int cur = 0;
    for (int d = 0; d < 8; ++d) {
        if ((vmax >> (d + 1)) == 0) break;           // block-uniform
        const bool valid = (v >> (d + 1)) > 0;
        const float* __restrict__ Qm = QT + (((v >> d) & 1) ? NMAT : 0);
        float2 acc = make_float2(0.f, 0.f);
        #pragma unroll 4
        for (int cc = 0; cc < 128; cc += 4) {
            float4 v4 = *(const float4*)&vs[cur][rg][cc];
            float2 q0 = *(const float2*)&Qm[(cc+0)*HALF + jj];
            float2 q1 = *(const float2*)&Qm[(cc+1)*HALF + jj];
            float2 q2 = *(const float2*)&Qm[(cc+2)*HALF + jj];
            float2 q3 = *(const float2*)&Qm[(cc+3)*HALF + jj];
            acc.x = fmaf(v4.x,q0.x, fmaf(v4.y,q1.x, fmaf(v4.z,q2.x, fmaf(v4.w,q3.x, acc.x))));
            acc.y = fmaf(v4.x,q0.y, fmaf(v4.y,q1.y, fmaf(v4.z,q2.y, fmaf(v4.w,q3.y, acc.y))));
        }
        if (valid) cv = acc;
        *(float2*)&vs[cur ^ 1][rg][jj] = cv;
        __syncthreads();
        cur ^= 1;
    }
    *(float2*)&P[v * HALF + jj] = cv;
}

// ---------------------------------------------------------------------------
// K2b: rows [256,4096), k-grouped, column-parallel.  ROUND-2 VERIFIED FORM.
// ---------------------------------------------------------------------------
__global__ __launch_bounds__(256) void path_upper(const float* __restrict__ QT,
                                                  float* __restrict__ P) {
    __shared__ __align__(16) float vs[2][8][HALF];   // double-buffered row vals
    const int t  = threadIdx.x;
    const int j  = t & 127;                // owned output column
    const int h  = t >> 7;                 // row half: rows h*4 .. h*4+3
    const int k  = 2 + (blockIdx.x >> 4);  // 30 k-values x 16 blocks = 480
    const int r0 = (blockIdx.x & 15) << 3; // 8 residues per block

    float acc[4];
    #pragma unroll
    for (int rr = 0; rr < 4; ++rr)
        acc[rr] = P[(128 + r0 + h * 4 + rr) * HALF + j];

    int p = 0;
    for (int d = 7; d < 13; ++d) {
        if ((k >> (d - 6)) == 0) break;              // block-uniform
        const float* __restrict__ Qm = QT + (((k >> (d - 7)) & 1) ? NMAT : 0);
        #pragma unroll
        for (int rr = 0; rr < 4; ++rr) vs[p][h * 4 + rr][j] = acc[rr];
        __syncthreads();                             // other buffer still live

        float nacc[4] = {0.f, 0.f, 0.f, 0.f};
        #pragma unroll 4
        for (int cc = 0; cc < 128; cc += 4) {
            float q0 = Qm[(cc + 0) * HALF + j];      // coalesced global dword
            float q1 = Qm[(cc + 1) * HALF + j];
            float q2 = Qm[(cc + 2) * HALF + j];
            float q3 = Qm[(cc + 3) * HALF + j];
            #pragma unroll
            for (int rr = 0; rr < 4; ++rr) {
                float4 v4 = *(const float4*)&vs[p][h * 4 + rr][cc];  // broadcast
                nacc[rr] = fmaf(v4.x, q0,
                           fmaf(v4.y, q1,
                           fmaf(v4.z, q2,
                           fmaf(v4.w, q3, nacc[rr]))));
            }
        }
        #pragma unroll
        for (int rr = 0; rr < 4; ++rr) acc[rr] = nacc[rr];
        p ^= 1;                                      // next step: other buffer
    }

    #pragma unroll
    for (int rr = 0; rr < 4; ++rr)
        P[((k << 7) | (r0 + h * 4 + rr)) * HALF + j] = acc[rr];
}

// ---------------------------------------------------------------------------
// K3: emit [B,S,256] = content ++ pos.  ROUND-2 VERIFIED FORM (NT stores).
// ---------------------------------------------------------------------------
__global__ __launch_bounds__(256) void emit_out(const int* __restrict__ tt,
                                                const int* __restrict__ tv,
                                                const int* __restrict__ np,
                                                const float* __restrict__ P,
                                                const float* __restrict__ emb,
                                                float* __restrict__ out) {
    const int i  = (blockIdx.x << 2) + (threadIdx.x >> 6);
    const int jj = (threadIdx.x & 63) << 2;
    const int ty = tt[i];
    const int v  = tv[i];
    f4 val;
    if (jj < 128) {
        if (ty == 0)      val = *(const f4*)&emb[jj];
        else if (ty == 1) val = *(const f4*)&emb[(v + 1) * HALF + jj];
        else if (ty == 2) val = *(const f4*)&emb[(v + 5) * HALF + jj];
        else if (ty == 4) {
            int vc = v < 0 ? 0 : (v > 4095 ? 4095 : v);
            val = *(const f4*)&P[vc * HALF + jj];
        } else if (v == -1) val = *(const f4*)&emb[10 * HALF + jj];
        else { f4 z = {0.f, 0.f, 0.f, 0.f}; val = z; }
    } else {
        const int p = np[i];
        val = *(const f4*)&P[p * HALF + (jj - 128)];
    }
    __builtin_nontemporal_store(val, (f4*)&out[i * 256 + jj]);
}

extern "C" void kernel_launch(void* const* d_in, const int* in_sizes, int n_in,
                              void* d_out, int out_size, void* d_ws, size_t ws_size,
                              hipStream_t stream) {
    const int*   token_types = (const int*)  d_in[0];
    const int*   token_vals  = (const int*)  d_in[1];
    const int*   node_pos    = (const int*)  d_in[2];
    const float* prim        = (const float*)d_in[3];
    const float* ident       = (const float*)d_in[4];
    const float* emb         = (const float*)d_in[5];
    float* out = (float*)d_out;

    // workspace: QT[2][128][128] | (gap) | P[4096][128]
    float* QT = (float*)d_ws;
    float* P  = (float*)((char*)d_ws + 262144);

    cayley_qt  <<<2,   512, 0, stream>>>(prim, QT);
    path_base  <<<64,  256, 0, stream>>>(QT, ident, P);     // rows [0,256)
    path_upper <<<480, 256, 0, stream>>>(QT, P);            // rows [256,4096)
    emit_out   <<<NTOK / 4, 256, 0, stream>>>(token_types, token_vals, node_pos,
                                              P, emb, out);
}